// Round 1
// baseline (409.695 us; speedup 1.0000x reference)
//
#include <hip/hip_runtime.h>

// Fused attention block for MI355X (gfx950).
// x[4096,768] fp32 -> QKV bf16 GEMM -> flash attention (12 heads, D=64) -> proj GEMM -> fp32 out.
// All matmuls use v_mfma_f32_16x16x32_bf16 with the HW-verified layouts:
//   A-frag: m=lane&15, k=quad*8+j ; B-frag: n=lane&15, k=quad*8+j ; C/D: row=quad*4+reg, col=lane&15.

typedef short bf16x8 __attribute__((ext_vector_type(8)));
typedef float f32x4 __attribute__((ext_vector_type(4)));
typedef unsigned short u16;

__device__ __forceinline__ u16 f2bf(float f) {
  unsigned u = __float_as_uint(f);
  u = (u + 0x7fffu + ((u >> 16) & 1u)) >> 16;  // RNE
  return (u16)u;
}

__device__ __forceinline__ void gload16(const void* g, void* l) {
  __builtin_amdgcn_global_load_lds(
      (const __attribute__((address_space(1))) unsigned int*)g,
      (__attribute__((address_space(3))) unsigned int*)l, 16, 0, 0);
}

// ---------------- fp32 -> bf16 cast, 4 elems/thread ----------------
__global__ void cast_bf16(const float* __restrict__ in, u16* __restrict__ out, int n4) {
  int i = blockIdx.x * blockDim.x + threadIdx.x;
  if (i >= n4) return;
  float4 v = ((const float4*)in)[i];
  ushort4 o;
  o.x = f2bf(v.x); o.y = f2bf(v.y); o.z = f2bf(v.z); o.w = f2bf(v.w);
  ((ushort4*)out)[i] = o;
}

// ---------------- m97-style GEMM: C[M,N] = A[M,K] * B[N,K]^T + bias ----------------
// MODE 0: scatter bf16 into q/k/v buffers [H=12][4096][64] (QKV projection, N=2304)
// MODE 1: fp32 out[M,N] (final projection, N=768)
template <int MODE>
__global__ __launch_bounds__(256, 2) void gemm_bt(
    const u16* __restrict__ A, const u16* __restrict__ B,
    const float* __restrict__ bias,
    u16* __restrict__ qb, u16* __restrict__ kbuf, u16* __restrict__ vb,
    float* __restrict__ outp, int K, int N) {
  __shared__ __align__(16) u16 As[128 * 32];
  __shared__ __align__(16) u16 Bs[128 * 32];
  const int tid = threadIdx.x, lane = tid & 63, w = tid >> 6;
  const int wr = w >> 1, wc = w & 1, quad = lane >> 4, l15 = lane & 15;
  const int m0 = blockIdx.y * 128, n0 = blockIdx.x * 128;

  f32x4 acc[4][4];
#pragma unroll
  for (int i = 0; i < 4; ++i)
#pragma unroll
    for (int j = 0; j < 4; ++j) acc[i][j] = (f32x4){0.f, 0.f, 0.f, 0.f};

  for (int k0 = 0; k0 < K; k0 += 32) {
    __syncthreads();
#pragma unroll
    for (int i = 0; i < 2; ++i) {
      int chunk = i * 256 + w * 64 + lane;     // 512 chunks of 16B per 8KB tile
      int row = chunk >> 2, kc = chunk & 3;
      gload16(A + (size_t)(m0 + row) * K + k0 + kc * 8, (char*)As + chunk * 16);
      gload16(B + (size_t)(n0 + row) * K + k0 + kc * 8, (char*)Bs + chunk * 16);
    }
    __syncthreads();
    bf16x8 af[4], bfr[4];
#pragma unroll
    for (int mi = 0; mi < 4; ++mi)
      af[mi] = *(const bf16x8*)&As[(wr * 64 + mi * 16 + l15) * 32 + quad * 8];
#pragma unroll
    for (int ni = 0; ni < 4; ++ni)
      bfr[ni] = *(const bf16x8*)&Bs[(wc * 64 + ni * 16 + l15) * 32 + quad * 8];
#pragma unroll
    for (int mi = 0; mi < 4; ++mi)
#pragma unroll
      for (int ni = 0; ni < 4; ++ni)
        acc[mi][ni] = __builtin_amdgcn_mfma_f32_16x16x32_bf16(af[mi], bfr[ni], acc[mi][ni], 0, 0, 0);
  }

#pragma unroll
  for (int mi = 0; mi < 4; ++mi) {
    int row = m0 + wr * 64 + mi * 16 + quad * 4;
#pragma unroll
    for (int ni = 0; ni < 4; ++ni) {
      int col = n0 + wc * 64 + ni * 16 + l15;
      float bv = bias[col];
      if (MODE == 0) {
        int t = col / 768;
        int rem = col - t * 768;
        int hh = rem >> 6, d = rem & 63;
        u16* dst = (t == 0 ? qb : (t == 1 ? kbuf : vb)) + (size_t)hh * 4096 * 64 + d;
#pragma unroll
        for (int r = 0; r < 4; ++r)
          dst[(size_t)(row + r) * 64] = f2bf(acc[mi][ni][r] + bv);
      } else {
#pragma unroll
        for (int r = 0; r < 4; ++r)
          outp[(size_t)(row + r) * N + col] = acc[mi][ni][r] + bv;
      }
    }
  }
}

// ---------------- flash attention: 1 block = (64 q-rows, head); 4 waves x 16-row strips ----------------
__global__ __launch_bounds__(256, 2) void flash_attn(
    const u16* __restrict__ qb, const u16* __restrict__ kb,
    const u16* __restrict__ vb, u16* __restrict__ ob) {
  constexpr float L2E = 1.4426950408889634f;
  const int h = blockIdx.y;
  const int q0 = blockIdx.x * 64;
  __shared__ __align__(16) u16 vt[64 * 72];      // V^T tile [d][key], stride 72 (pad)
  __shared__ __align__(16) u16 pl[4][16 * 72];   // per-wave P strip [row][key], stride 72
  const int tid = threadIdx.x, lane = tid & 63, w = tid >> 6;
  const int quad = lane >> 4, l15 = lane & 15;
  const u16* qh = qb + (size_t)h * 4096 * 64;
  const u16* kh = kb + (size_t)h * 4096 * 64;
  const u16* vh = vb + (size_t)h * 4096 * 64;

  // Q A-frags for the whole K loop: row = q0 + w*16 + (lane&15), k = kc*32 + quad*8 + j
  bf16x8 qf[2];
#pragma unroll
  for (int kc = 0; kc < 2; ++kc)
    qf[kc] = *(const bf16x8*)&qh[(size_t)(q0 + w * 16 + l15) * 64 + kc * 32 + quad * 8];

  f32x4 oacc[4];
#pragma unroll
  for (int dt = 0; dt < 4; ++dt) oacc[dt] = (f32x4){0.f, 0.f, 0.f, 0.f};
  float mprev[4], lsum[4];
#pragma unroll
  for (int r = 0; r < 4; ++r) { mprev[r] = -1e30f; lsum[r] = 0.f; }

  for (int kt = 0; kt < 4096; kt += 64) {
    __syncthreads();  // protect vt from previous iteration's readers
    {  // stage V^T: thread -> key = tid&63, d-range = (tid>>6)*16 .. +15
      int key = tid & 63, db = (tid >> 6) * 16;
      bf16x8 v0 = *(const bf16x8*)&vh[(size_t)(kt + key) * 64 + db];
      bf16x8 v1 = *(const bf16x8*)&vh[(size_t)(kt + key) * 64 + db + 8];
#pragma unroll
      for (int j = 0; j < 8; ++j) {
        vt[(db + j) * 72 + key] = (u16)v0[j];
        vt[(db + 8 + j) * 72 + key] = (u16)v1[j];
      }
    }
    __syncthreads();

    // S strip [16 rows][64 keys] = Q * K^T, K B-frags straight from global (L2-resident)
    f32x4 sacc[4];
#pragma unroll
    for (int nt = 0; nt < 4; ++nt) sacc[nt] = (f32x4){0.f, 0.f, 0.f, 0.f};
#pragma unroll
    for (int nt = 0; nt < 4; ++nt) {
      bf16x8 kf0 = *(const bf16x8*)&kh[(size_t)(kt + nt * 16 + l15) * 64 + quad * 8];
      bf16x8 kf1 = *(const bf16x8*)&kh[(size_t)(kt + nt * 16 + l15) * 64 + 32 + quad * 8];
      sacc[nt] = __builtin_amdgcn_mfma_f32_16x16x32_bf16(qf[0], kf0, sacc[nt], 0, 0, 0);
      sacc[nt] = __builtin_amdgcn_mfma_f32_16x16x32_bf16(qf[1], kf1, sacc[nt], 0, 0, 0);
    }

    // online softmax; row r' = quad*4+r, spread over the 16 lanes sharing this quad
    float alpha[4];
#pragma unroll
    for (int r = 0; r < 4; ++r) {
      float s0 = sacc[0][r] * 8.f, s1 = sacc[1][r] * 8.f;  // logits * sqrt(D) (reference quirk)
      float s2 = sacc[2][r] * 8.f, s3 = sacc[3][r] * 8.f;
      float mx = fmaxf(fmaxf(s0, s1), fmaxf(s2, s3));
      mx = fmaxf(mx, __shfl_xor(mx, 1));
      mx = fmaxf(mx, __shfl_xor(mx, 2));
      mx = fmaxf(mx, __shfl_xor(mx, 4));
      mx = fmaxf(mx, __shfl_xor(mx, 8));
      float mnew = fmaxf(mprev[r], mx);
      alpha[r] = exp2f((mprev[r] - mnew) * L2E);
      float p0 = exp2f((s0 - mnew) * L2E);
      float p1 = exp2f((s1 - mnew) * L2E);
      float p2 = exp2f((s2 - mnew) * L2E);
      float p3 = exp2f((s3 - mnew) * L2E);
      int rowoff = (quad * 4 + r) * 72 + l15;
      pl[w][rowoff]      = f2bf(p0);
      pl[w][rowoff + 16] = f2bf(p1);
      pl[w][rowoff + 32] = f2bf(p2);
      pl[w][rowoff + 48] = f2bf(p3);
      float ls = p0 + p1 + p2 + p3;
      ls += __shfl_xor(ls, 1);
      ls += __shfl_xor(ls, 2);
      ls += __shfl_xor(ls, 4);
      ls += __shfl_xor(ls, 8);
      lsum[r] = lsum[r] * alpha[r] + ls;
      mprev[r] = mnew;
    }
#pragma unroll
    for (int dt = 0; dt < 4; ++dt) {
      oacc[dt][0] *= alpha[0]; oacc[dt][1] *= alpha[1];
      oacc[dt][2] *= alpha[2]; oacc[dt][3] *= alpha[3];
    }
    __syncthreads();  // P visible (and vt stable) for PV

    // O += P * V : A = P (LDS round-trip), B = V^T from vt
    bf16x8 pf0 = *(const bf16x8*)&pl[w][l15 * 72 + quad * 8];
    bf16x8 pf1 = *(const bf16x8*)&pl[w][l15 * 72 + 32 + quad * 8];
#pragma unroll
    for (int dt = 0; dt < 4; ++dt) {
      bf16x8 vf0 = *(const bf16x8*)&vt[(dt * 16 + l15) * 72 + quad * 8];
      bf16x8 vf1 = *(const bf16x8*)&vt[(dt * 16 + l15) * 72 + 32 + quad * 8];
      oacc[dt] = __builtin_amdgcn_mfma_f32_16x16x32_bf16(pf0, vf0, oacc[dt], 0, 0, 0);
      oacc[dt] = __builtin_amdgcn_mfma_f32_16x16x32_bf16(pf1, vf1, oacc[dt], 0, 0, 0);
    }
  }

  // epilogue: out[n][h*64+d] bf16, normalized by lsum
#pragma unroll
  for (int dt = 0; dt < 4; ++dt) {
    int d = dt * 16 + l15;
#pragma unroll
    for (int r = 0; r < 4; ++r) {
      int row = q0 + w * 16 + quad * 4 + r;
      ob[(size_t)row * 768 + h * 64 + d] = f2bf(oacc[dt][r] / lsum[r]);
    }
  }
}

extern "C" void kernel_launch(void* const* d_in, const int* in_sizes, int n_in,
                              void* d_out, int out_size, void* d_ws, size_t ws_size,
                              hipStream_t stream) {
  const float* x      = (const float*)d_in[0];
  const float* qkv_w  = (const float*)d_in[1];
  const float* qkv_b  = (const float*)d_in[2];
  const float* proj_w = (const float*)d_in[3];
  const float* proj_b = (const float*)d_in[4];
  float* out = (float*)d_out;

  const int N = 4096, C = 768, H = 12, D = 64, C3 = 2304;
  char* ws = (char*)d_ws;
  size_t off = 0;
  u16* xb    = (u16*)(ws + off); off += (size_t)N * C * 2;       // 6.29 MB (reused as attn-out)
  u16* wqkv  = (u16*)(ws + off); off += (size_t)C3 * C * 2;      // 3.54 MB
  u16* wproj = (u16*)(ws + off); off += (size_t)C * C * 2;       // 1.18 MB
  u16* qbuf  = (u16*)(ws + off); off += (size_t)H * N * D * 2;   // 6.29 MB
  u16* kbuf  = (u16*)(ws + off); off += (size_t)H * N * D * 2;
  u16* vbuf  = (u16*)(ws + off); off += (size_t)H * N * D * 2;   // total ~29.9 MB
  u16* aob = xb;  // alias: xb dead after QKV GEMM

  cast_bf16<<<N * C / 1024, 256, 0, stream>>>(x, xb, N * C / 4);
  cast_bf16<<<C3 * C / 1024, 256, 0, stream>>>(qkv_w, wqkv, C3 * C / 4);
  cast_bf16<<<C * C / 1024, 256, 0, stream>>>(proj_w, wproj, C * C / 4);

  dim3 g1(C3 / 128, N / 128);  // 18 x 32
  gemm_bt<0><<<g1, 256, 0, stream>>>(xb, wqkv, qkv_b, qbuf, kbuf, vbuf, nullptr, C, C3);

  dim3 g2(N / 64, H);          // 64 x 12
  flash_attn<<<g2, 256, 0, stream>>>(qbuf, kbuf, vbuf, aob);

  dim3 g3(C / 128, N / 128);   // 6 x 32
  gemm_bt<1><<<g3, 256, 0, stream>>>(aob, wproj, proj_b, nullptr, nullptr, nullptr, out, C, C);
}